// Round 11
// baseline (128.648 us; speedup 1.0000x reference)
//
#include <hip/hip_runtime.h>
#include <hip/hip_bf16.h>

#define B_Q 4096
#define R_T 500
#define D_E 64
#define N_N 100000
#define E_E 3200000

typedef int   iv4 __attribute__((ext_vector_type(4)));
typedef float fv4 __attribute__((ext_vector_type(4)));

// ws layout (ints): Cm[B*R] | rel_freq[R] | slot[N] | ... | dummyCm @ +64M ints
#define OFF_RF    ((size_t)B_Q * R_T)
#define OFF_SLOT  (OFF_RF + R_T)
#define OFF_DUMMY ((size_t)64 * 1024 * 1024)   // 256 MB in, far from live data

// ---------------------------------------------------------------------------
// init: zero Cm+rel_freq, sentinel slot. uint4 stores, one dispatch.
// ---------------------------------------------------------------------------
__global__ __launch_bounds__(256) void k_init(int* __restrict__ ws) {
    const int t = blockIdx.x * blockDim.x + threadIdx.x;
    uint4* cm4 = (uint4*)ws;
    if (t < (B_Q * R_T) / 4) cm4[t] = make_uint4(0, 0, 0, 0);
    uint4* sl4 = (uint4*)(ws + OFF_SLOT);
    if (t < N_N / 4) sl4[t] = make_uint4(0x7f7f7f7fu, 0x7f7f7f7fu, 0x7f7f7f7fu, 0x7f7f7f7fu);
    if (t < R_T) ws[OFF_RF + t] = 0;
}

// ---------------------------------------------------------------------------
// slot[n] = min b with qents[b]==n (dedups repeated query entities)
// ---------------------------------------------------------------------------
__global__ __launch_bounds__(256) void k_build_slot(const int* __restrict__ qents,
                                                    int* __restrict__ ws) {
    int b = blockIdx.x * blockDim.x + threadIdx.x;
    if (b < B_Q) {
        int q = qents[b];
        atomicMin(&ws[OFF_SLOT + q], b);
    }
}

// ---------------------------------------------------------------------------
// DIAGNOSTIC dummy scatter: identical probe/atomic pattern, no LDS hist,
// accumulates into the unused region at OFF_DUMMY (never read -> output
// deterministic). dur - 87us isolates t_scatter_nohist@512.
// ---------------------------------------------------------------------------
__global__ __launch_bounds__(256) void k_edge_scatter_dummy(const int* __restrict__ ei,
                                                            const int* __restrict__ et,
                                                            int* __restrict__ ws) {
    const int* __restrict__ slot = ws + OFF_SLOT;
    int* __restrict__       Cm   = ws + OFF_DUMMY;

    const int nthr = gridDim.x * blockDim.x;
    const int t    = blockIdx.x * blockDim.x + threadIdx.x;
    for (int g = t; g < E_E / 4; g += nthr) {
        const int e0 = g * 4;
        const iv4 s4 = __builtin_nontemporal_load((const iv4*)(ei + e0));
        const iv4 d4 = __builtin_nontemporal_load((const iv4*)(ei + E_E + e0));
        const iv4 t4 = __builtin_nontemporal_load((const iv4*)(et + e0));
        #pragma unroll
        for (int j = 0; j < 4; ++j) {
            const int s  = s4[j];
            const int d  = d4[j];
            const int ty = t4[j];
            const int ss = slot[s];
            if (ss < B_Q) atomicAdd(&Cm[(size_t)ss * R_T + ty], 1);
            if (d != s) {
                const int sd = slot[d];
                if (sd < B_Q) atomicAdd(&Cm[(size_t)sd * R_T + ty], 1);
            }
        }
    }
}

// ---------------------------------------------------------------------------
// R6-proven scatter: 512 blocks, grid-stride, direct slot probes, int4
// nontemporal edge loads, LDS hist -> 512x500 atomics at flush.
// ---------------------------------------------------------------------------
__global__ __launch_bounds__(256) void k_edge_scatter(const int* __restrict__ ei,
                                                      const int* __restrict__ et,
                                                      int* __restrict__ ws) {
    __shared__ int hist[R_T];
    for (int i = threadIdx.x; i < R_T; i += blockDim.x) hist[i] = 0;
    __syncthreads();

    const int* __restrict__ slot = ws + OFF_SLOT;
    int* __restrict__       Cm   = ws;

    const int nthr = gridDim.x * blockDim.x;
    const int t    = blockIdx.x * blockDim.x + threadIdx.x;
    for (int g = t; g < E_E / 4; g += nthr) {
        const int e0 = g * 4;
        const iv4 s4 = __builtin_nontemporal_load((const iv4*)(ei + e0));
        const iv4 d4 = __builtin_nontemporal_load((const iv4*)(ei + E_E + e0));
        const iv4 t4 = __builtin_nontemporal_load((const iv4*)(et + e0));
        #pragma unroll
        for (int j = 0; j < 4; ++j) {
            const int s  = s4[j];
            const int d  = d4[j];
            const int ty = t4[j];
            atomicAdd(&hist[ty], 1);
            const int ss = slot[s];
            if (ss < B_Q) atomicAdd(&Cm[(size_t)ss * R_T + ty], 1);
            if (d != s) {
                const int sd = slot[d];
                if (sd < B_Q) atomicAdd(&Cm[(size_t)sd * R_T + ty], 1);
            }
        }
    }
    __syncthreads();
    for (int i = threadIdx.x; i < R_T; i += blockDim.x) {
        int v = hist[i];
        if (v) atomicAdd(&ws[OFF_RF + i], v);
    }
}

// ---------------------------------------------------------------------------
// One wave per query; 4 waves/block, ZERO block barriers. R6-proven body.
// ---------------------------------------------------------------------------
__global__ __launch_bounds__(256) void k_gate(
    const float* __restrict__ RE,
    const int* __restrict__ qrels, const int* __restrict__ qents,
    const int* __restrict__ ws,
    const float* __restrict__ W1, const float* __restrict__ b1,
    const float* __restrict__ W2, const float* __restrict__ b2,
    const float* __restrict__ W3, const float* __restrict__ b3,
    const float* __restrict__ W4, const float* __restrict__ b4,
    float* __restrict__ out)
{
    __shared__ int   sIdx[4][512];
    __shared__ float sCnt[4][512];
    __shared__ float sF [4][132];
    __shared__ float sH1[4][64];
    __shared__ float sH2[4][32];
    __shared__ float sG [4][16];

    const int wid  = threadIdx.x >> 6;
    const int lane = threadIdx.x & 63;
    const int b    = blockIdx.x * 4 + wid;   // grid is exactly B/4

    const int q  = qents[b];
    const int qr = qrels[b];
    const int sl = ws[OFF_SLOT + q];
    const int* __restrict__   crow = ws + (size_t)sl * R_T;
    const float* __restrict__ REb  = RE + (size_t)b * (R_T * D_E);

    float reb = REb[qr * D_E + lane];

    // --- compact nonzero counts (ascending r, deterministic) ---
    int nnz = 0, degl = 0;
    for (int base = 0; base < R_T; base += 64) {
        int r = base + lane;
        int c = (r < R_T) ? crow[r] : 0;
        degl += c;
        unsigned long long m = __ballot(c != 0);
        if (c != 0) {
            int pos = nnz + (int)__popcll(m & ((1ull << lane) - 1ull));
            sIdx[wid][pos] = r;
            sCnt[wid][pos] = (float)c;
        }
        nnz += (int)__popcll(m);
    }
    // pad to multiple of 4 with zero-count entries (row 0 -> valid addr, 0 fma)
    if (lane < 4) {
        sIdx[wid][nnz + lane] = 0;
        sCnt[wid][nnz + lane] = 0.f;
    }
    #pragma unroll
    for (int off = 32; off; off >>= 1) degl += __shfl_xor(degl, off, 64);

    // --- sparse weighted sum: 4 rows/iter, branch-free ---
    const int g = lane >> 4;        // row group 0..3
    const int l = lane & 15;        // dwordx4 slot within row
    fv4 acc = {0.f, 0.f, 0.f, 0.f};
    #pragma unroll 4
    for (int k = 0; k < nnz; k += 4) {
        int   r = sIdx[wid][k + g];
        float c = sCnt[wid][k + g];
        fv4 v = __builtin_nontemporal_load((const fv4*)(REb + r * D_E + 4 * l));
        acc[0] = fmaf(c, v[0], acc[0]);
        acc[1] = fmaf(c, v[1], acc[1]);
        acc[2] = fmaf(c, v[2], acc[2]);
        acc[3] = fmaf(c, v[3], acc[3]);
    }
    #pragma unroll
    for (int off = 16; off <= 32; off <<= 1) {
        acc[0] += __shfl_xor(acc[0], off, 64);
        acc[1] += __shfl_xor(acc[1], off, 64);
        acc[2] += __shfl_xor(acc[2], off, 64);
        acc[3] += __shfl_xor(acc[3], off, 64);
    }

    const float tot = (float)degl;
    const float inv = (degl > 0) ? (1.f / tot) : 0.f;

    sF[wid][lane] = reb;
    if (lane < 16) {
        float4* dst = (float4*)&sF[wid][64 + 4 * lane];
        *dst = make_float4(acc[0] * inv, acc[1] * inv, acc[2] * inv, acc[3] * inv);
    }
    if (lane == 0) {
        const float invE = (float)(1.0 / (double)E_E);
        float rf   = fminf((float)ws[OFF_RF + qr] * invE, 1.f);
        float dn   = fminf(tot * invE, 1.f);
        float dens = fminf((float)((double)E_E / ((double)N_N * (double)N_N)), 1.f);
        sF[wid][128] = rf;
        sF[wid][129] = dn;
        sF[wid][130] = rf;
        sF[wid][131] = dens;
    }
    // (no barrier: same-wave LDS write->read is in-order)

    // --- layer 1: 132 -> 64 ---
    float h = b1[lane];
    #pragma unroll 4
    for (int i = 0; i < 2 * D_E + 4; ++i)
        h = fmaf(sF[wid][i], W1[i * D_E + lane], h);
    sH1[wid][lane] = fmaxf(h, 0.f);

    // --- layer 2: 64 -> 32 ---
    if (lane < 32) {
        float s2 = b2[lane];
        #pragma unroll 4
        for (int i = 0; i < D_E; ++i)
            s2 = fmaf(sH1[wid][i], W2[i * 32 + lane], s2);
        sH2[wid][lane] = fmaxf(s2, 0.f);
    }

    // --- layer 3: 32 -> 16 ---
    if (lane < 16) {
        float s3 = b3[lane];
        #pragma unroll
        for (int i = 0; i < 32; ++i)
            s3 = fmaf(sH2[wid][i], W3[i * 16 + lane], s3);
        sG[wid][lane] = fmaxf(s3, 0.f);
    }

    // --- gate: 16 -> 1, sigmoid ---
    if (lane == 0) {
        float s4 = b4[0];
        #pragma unroll
        for (int i = 0; i < 16; ++i)
            s4 = fmaf(sG[wid][i], W4[i], s4);
        out[b] = 1.f / (1.f + expf(-s4));
    }
}

extern "C" void kernel_launch(void* const* d_in, const int* in_sizes, int n_in,
                              void* d_out, int out_size, void* d_ws, size_t ws_size,
                              hipStream_t stream) {
    const float* RE    = (const float*)d_in[0];
    const int*   qrels = (const int*)d_in[1];
    const int*   qents = (const int*)d_in[2];
    const int*   ei    = (const int*)d_in[3];
    const int*   et    = (const int*)d_in[4];
    const float* W1    = (const float*)d_in[5];
    const float* b1    = (const float*)d_in[6];
    const float* W2    = (const float*)d_in[7];
    const float* b2    = (const float*)d_in[8];
    const float* W3    = (const float*)d_in[9];
    const float* b3    = (const float*)d_in[10];
    const float* W4    = (const float*)d_in[11];
    const float* b4    = (const float*)d_in[12];
    float* out = (float*)d_out;
    int*   ws  = (int*)d_ws;

    k_init<<<2000, 256, 0, stream>>>(ws);
    k_build_slot<<<(B_Q + 255) / 256, 256, 0, stream>>>(qents, ws);
    // DIAGNOSTIC: dummy scatter (unused output) => dur - 87us = t_scatter@512
    k_edge_scatter_dummy<<<512, 256, 0, stream>>>(ei, et, ws);
    k_edge_scatter<<<512, 256, 0, stream>>>(ei, et, ws);
    k_gate<<<B_Q / 4, 256, 0, stream>>>(RE, qrels, qents, ws,
                                        W1, b1, W2, b2, W3, b3, W4, b4, out);
}

// Round 12
// 90.869 us; speedup vs baseline: 1.4158x; 1.4158x over previous
//
#include <hip/hip_runtime.h>
#include <hip/hip_bf16.h>

#define B_Q 4096
#define R_T 500
#define D_E 64
#define N_N 100000
#define E_E 3200000
#define BM_W ((N_N + 31) / 32)   // 3125 words = 12.5 KB, L1-resident

typedef int   iv4 __attribute__((ext_vector_type(4)));
typedef float fv4 __attribute__((ext_vector_type(4)));

// ws layout (ints): Cm[B*R] | rel_freq[R] | slot[N] | bitmap[BM_W]
#define OFF_RF   ((size_t)B_Q * R_T)
#define OFF_SLOT (OFF_RF + R_T)
#define OFF_BM   (OFF_SLOT + N_N)

// ---------------------------------------------------------------------------
// init: zero Cm+rel_freq+bitmap, sentinel slot. uint4 stores, one dispatch.
// ---------------------------------------------------------------------------
__global__ __launch_bounds__(256) void k_init(int* __restrict__ ws) {
    const int t = blockIdx.x * blockDim.x + threadIdx.x;
    uint4* cm4 = (uint4*)ws;
    if (t < (B_Q * R_T) / 4) cm4[t] = make_uint4(0, 0, 0, 0);
    uint4* sl4 = (uint4*)(ws + OFF_SLOT);
    if (t < N_N / 4) sl4[t] = make_uint4(0x7f7f7f7fu, 0x7f7f7f7fu, 0x7f7f7f7fu, 0x7f7f7f7fu);
    if (t < R_T) ws[OFF_RF + t] = 0;
    if (t >= R_T && t < R_T + BM_W) ws[OFF_BM + (t - R_T)] = 0;
}

// ---------------------------------------------------------------------------
// slot[n] = min b with qents[b]==n; bitmap bit marks queried entities
// ---------------------------------------------------------------------------
__global__ __launch_bounds__(256) void k_build_slot(const int* __restrict__ qents,
                                                    int* __restrict__ ws) {
    int b = blockIdx.x * blockDim.x + threadIdx.x;
    if (b < B_Q) {
        int q = qents[b];
        atomicMin(&ws[OFF_SLOT + q], b);
        atomicOr(&ws[OFF_BM + (q >> 5)], 1 << (q & 31));
    }
}

// ---------------------------------------------------------------------------
// R6 shape (512 blocks, grid-stride, LDS hist) + ONE change: probe the
// 12.5KB global bitmap first (L1-resident; nt edge loads don't evict it).
// ~96% of endpoints filter out as L1 hits; only ~4% touch L2 slot[].
// ---------------------------------------------------------------------------
__global__ __launch_bounds__(256) void k_edge_scatter(const int* __restrict__ ei,
                                                      const int* __restrict__ et,
                                                      int* __restrict__ ws) {
    __shared__ int hist[R_T];
    for (int i = threadIdx.x; i < R_T; i += blockDim.x) hist[i] = 0;
    __syncthreads();

    const unsigned* __restrict__ bm   = (const unsigned*)(ws + OFF_BM);
    const int* __restrict__      slot = ws + OFF_SLOT;
    int* __restrict__            Cm   = ws;

    const int nthr = gridDim.x * blockDim.x;
    const int t    = blockIdx.x * blockDim.x + threadIdx.x;
    for (int g = t; g < E_E / 4; g += nthr) {
        const int e0 = g * 4;
        const iv4 s4 = __builtin_nontemporal_load((const iv4*)(ei + e0));
        const iv4 d4 = __builtin_nontemporal_load((const iv4*)(ei + E_E + e0));
        const iv4 t4 = __builtin_nontemporal_load((const iv4*)(et + e0));
        #pragma unroll
        for (int j = 0; j < 4; ++j) {
            const int s  = s4[j];
            const int d  = d4[j];
            const int ty = t4[j];
            atomicAdd(&hist[ty], 1);
            if ((bm[s >> 5] >> (s & 31)) & 1u) {
                const int ss = slot[s];
                if (ss < B_Q) atomicAdd(&Cm[(size_t)ss * R_T + ty], 1);
            }
            if (d != s && ((bm[d >> 5] >> (d & 31)) & 1u)) {
                const int sd = slot[d];
                if (sd < B_Q) atomicAdd(&Cm[(size_t)sd * R_T + ty], 1);
            }
        }
    }
    __syncthreads();
    for (int i = threadIdx.x; i < R_T; i += blockDim.x) {
        int v = hist[i];
        if (v) atomicAdd(&ws[OFF_RF + i], v);
    }
}

// ---------------------------------------------------------------------------
// One wave per query; 4 waves/block, ZERO block barriers. R6-proven body.
// ---------------------------------------------------------------------------
__global__ __launch_bounds__(256) void k_gate(
    const float* __restrict__ RE,
    const int* __restrict__ qrels, const int* __restrict__ qents,
    const int* __restrict__ ws,
    const float* __restrict__ W1, const float* __restrict__ b1,
    const float* __restrict__ W2, const float* __restrict__ b2,
    const float* __restrict__ W3, const float* __restrict__ b3,
    const float* __restrict__ W4, const float* __restrict__ b4,
    float* __restrict__ out)
{
    __shared__ int   sIdx[4][512];
    __shared__ float sCnt[4][512];
    __shared__ float sF [4][132];
    __shared__ float sH1[4][64];
    __shared__ float sH2[4][32];
    __shared__ float sG [4][16];

    const int wid  = threadIdx.x >> 6;
    const int lane = threadIdx.x & 63;
    const int b    = blockIdx.x * 4 + wid;   // grid is exactly B/4

    const int q  = qents[b];
    const int qr = qrels[b];
    const int sl = ws[OFF_SLOT + q];
    const int* __restrict__   crow = ws + (size_t)sl * R_T;
    const float* __restrict__ REb  = RE + (size_t)b * (R_T * D_E);

    float reb = REb[qr * D_E + lane];

    // --- compact nonzero counts (ascending r, deterministic) ---
    int nnz = 0, degl = 0;
    for (int base = 0; base < R_T; base += 64) {
        int r = base + lane;
        int c = (r < R_T) ? crow[r] : 0;
        degl += c;
        unsigned long long m = __ballot(c != 0);
        if (c != 0) {
            int pos = nnz + (int)__popcll(m & ((1ull << lane) - 1ull));
            sIdx[wid][pos] = r;
            sCnt[wid][pos] = (float)c;
        }
        nnz += (int)__popcll(m);
    }
    // pad to multiple of 4 with zero-count entries (row 0 -> valid addr, 0 fma)
    if (lane < 4) {
        sIdx[wid][nnz + lane] = 0;
        sCnt[wid][nnz + lane] = 0.f;
    }
    #pragma unroll
    for (int off = 32; off; off >>= 1) degl += __shfl_xor(degl, off, 64);

    // --- sparse weighted sum: 4 rows/iter, branch-free ---
    const int g = lane >> 4;        // row group 0..3
    const int l = lane & 15;        // dwordx4 slot within row
    fv4 acc = {0.f, 0.f, 0.f, 0.f};
    #pragma unroll 4
    for (int k = 0; k < nnz; k += 4) {
        int   r = sIdx[wid][k + g];
        float c = sCnt[wid][k + g];
        fv4 v = __builtin_nontemporal_load((const fv4*)(REb + r * D_E + 4 * l));
        acc[0] = fmaf(c, v[0], acc[0]);
        acc[1] = fmaf(c, v[1], acc[1]);
        acc[2] = fmaf(c, v[2], acc[2]);
        acc[3] = fmaf(c, v[3], acc[3]);
    }
    #pragma unroll
    for (int off = 16; off <= 32; off <<= 1) {
        acc[0] += __shfl_xor(acc[0], off, 64);
        acc[1] += __shfl_xor(acc[1], off, 64);
        acc[2] += __shfl_xor(acc[2], off, 64);
        acc[3] += __shfl_xor(acc[3], off, 64);
    }

    const float tot = (float)degl;
    const float inv = (degl > 0) ? (1.f / tot) : 0.f;

    sF[wid][lane] = reb;
    if (lane < 16) {
        float4* dst = (float4*)&sF[wid][64 + 4 * lane];
        *dst = make_float4(acc[0] * inv, acc[1] * inv, acc[2] * inv, acc[3] * inv);
    }
    if (lane == 0) {
        const float invE = (float)(1.0 / (double)E_E);
        float rf   = fminf((float)ws[OFF_RF + qr] * invE, 1.f);
        float dn   = fminf(tot * invE, 1.f);
        float dens = fminf((float)((double)E_E / ((double)N_N * (double)N_N)), 1.f);
        sF[wid][128] = rf;
        sF[wid][129] = dn;
        sF[wid][130] = rf;
        sF[wid][131] = dens;
    }
    // (no barrier: same-wave LDS write->read is in-order)

    // --- layer 1: 132 -> 64 ---
    float h = b1[lane];
    #pragma unroll 4
    for (int i = 0; i < 2 * D_E + 4; ++i)
        h = fmaf(sF[wid][i], W1[i * D_E + lane], h);
    sH1[wid][lane] = fmaxf(h, 0.f);

    // --- layer 2: 64 -> 32 ---
    if (lane < 32) {
        float s2 = b2[lane];
        #pragma unroll 4
        for (int i = 0; i < D_E; ++i)
            s2 = fmaf(sH1[wid][i], W2[i * 32 + lane], s2);
        sH2[wid][lane] = fmaxf(s2, 0.f);
    }

    // --- layer 3: 32 -> 16 ---
    if (lane < 16) {
        float s3 = b3[lane];
        #pragma unroll
        for (int i = 0; i < 32; ++i)
            s3 = fmaf(sH2[wid][i], W3[i * 16 + lane], s3);
        sG[wid][lane] = fmaxf(s3, 0.f);
    }

    // --- gate: 16 -> 1, sigmoid ---
    if (lane == 0) {
        float s4 = b4[0];
        #pragma unroll
        for (int i = 0; i < 16; ++i)
            s4 = fmaf(sG[wid][i], W4[i], s4);
        out[b] = 1.f / (1.f + expf(-s4));
    }
}

extern "C" void kernel_launch(void* const* d_in, const int* in_sizes, int n_in,
                              void* d_out, int out_size, void* d_ws, size_t ws_size,
                              hipStream_t stream) {
    const float* RE    = (const float*)d_in[0];
    const int*   qrels = (const int*)d_in[1];
    const int*   qents = (const int*)d_in[2];
    const int*   ei    = (const int*)d_in[3];
    const int*   et    = (const int*)d_in[4];
    const float* W1    = (const float*)d_in[5];
    const float* b1    = (const float*)d_in[6];
    const float* W2    = (const float*)d_in[7];
    const float* b2    = (const float*)d_in[8];
    const float* W3    = (const float*)d_in[9];
    const float* b3    = (const float*)d_in[10];
    const float* W4    = (const float*)d_in[11];
    const float* b4    = (const float*)d_in[12];
    float* out = (float*)d_out;
    int*   ws  = (int*)d_ws;

    k_init<<<2000, 256, 0, stream>>>(ws);
    k_build_slot<<<(B_Q + 255) / 256, 256, 0, stream>>>(qents, ws);
    k_edge_scatter<<<512, 256, 0, stream>>>(ei, et, ws);
    k_gate<<<B_Q / 4, 256, 0, stream>>>(RE, qrels, qents, ws,
                                        W1, b1, W2, b2, W3, b3, W4, b4, out);
}

// Round 13
// 84.447 us; speedup vs baseline: 1.5234x; 1.0760x over previous
//
#include <hip/hip_runtime.h>
#include <hip/hip_bf16.h>

#define B_Q 4096
#define R_T 500
#define D_E 64
#define N_N 100000
#define E_E 3200000

typedef int   iv4 __attribute__((ext_vector_type(4)));
typedef float fv4 __attribute__((ext_vector_type(4)));

// ws layout (ints): Cm[B*R] | rel_freq[R] | slot[N]
#define OFF_RF   ((size_t)B_Q * R_T)
#define OFF_SLOT (OFF_RF + R_T)

// ---------------------------------------------------------------------------
// init: zero Cm+rel_freq, sentinel slot. uint4 stores, one dispatch.
// ---------------------------------------------------------------------------
__global__ __launch_bounds__(256) void k_init(int* __restrict__ ws) {
    const int t = blockIdx.x * blockDim.x + threadIdx.x;
    uint4* cm4 = (uint4*)ws;
    if (t < (B_Q * R_T) / 4) cm4[t] = make_uint4(0, 0, 0, 0);
    uint4* sl4 = (uint4*)(ws + OFF_SLOT);
    if (t < N_N / 4) sl4[t] = make_uint4(0x7f7f7f7fu, 0x7f7f7f7fu, 0x7f7f7f7fu, 0x7f7f7f7fu);
    if (t < R_T) ws[OFF_RF + t] = 0;
}

// ---------------------------------------------------------------------------
// slot[n] = min b with qents[b]==n (dedups repeated query entities)
// ---------------------------------------------------------------------------
__global__ __launch_bounds__(256) void k_build_slot(const int* __restrict__ qents,
                                                    int* __restrict__ ws) {
    int b = blockIdx.x * blockDim.x + threadIdx.x;
    if (b < B_Q) {
        int q = qents[b];
        atomicMin(&ws[OFF_SLOT + q], b);
    }
}

// ---------------------------------------------------------------------------
// R6 shape: 512 blocks, grid-stride, direct slot probes, LDS hist.
// ONLY change vs R6: plain (cacheable) int4 edge loads — edges are
// L3-resident across graph replays; nt hints forced HBM refetch.
// ---------------------------------------------------------------------------
__global__ __launch_bounds__(256) void k_edge_scatter(const int* __restrict__ ei,
                                                      const int* __restrict__ et,
                                                      int* __restrict__ ws) {
    __shared__ int hist[R_T];
    for (int i = threadIdx.x; i < R_T; i += blockDim.x) hist[i] = 0;
    __syncthreads();

    const int* __restrict__ slot = ws + OFF_SLOT;
    int* __restrict__       Cm   = ws;

    const int nthr = gridDim.x * blockDim.x;
    const int t    = blockIdx.x * blockDim.x + threadIdx.x;
    for (int g = t; g < E_E / 4; g += nthr) {
        const int e0 = g * 4;
        const iv4 s4 = *(const iv4*)(ei + e0);
        const iv4 d4 = *(const iv4*)(ei + E_E + e0);
        const iv4 t4 = *(const iv4*)(et + e0);
        #pragma unroll
        for (int j = 0; j < 4; ++j) {
            const int s  = s4[j];
            const int d  = d4[j];
            const int ty = t4[j];
            atomicAdd(&hist[ty], 1);
            const int ss = slot[s];
            if (ss < B_Q) atomicAdd(&Cm[(size_t)ss * R_T + ty], 1);
            if (d != s) {
                const int sd = slot[d];
                if (sd < B_Q) atomicAdd(&Cm[(size_t)sd * R_T + ty], 1);
            }
        }
    }
    __syncthreads();
    for (int i = threadIdx.x; i < R_T; i += blockDim.x) {
        int v = hist[i];
        if (v) atomicAdd(&ws[OFF_RF + i], v);
    }
}

// ---------------------------------------------------------------------------
// One wave per query; 4 waves/block, ZERO block barriers. R6 body with
// plain (cacheable) fv4 row loads — RE rows are L3-resident across replays.
// ---------------------------------------------------------------------------
__global__ __launch_bounds__(256) void k_gate(
    const float* __restrict__ RE,
    const int* __restrict__ qrels, const int* __restrict__ qents,
    const int* __restrict__ ws,
    const float* __restrict__ W1, const float* __restrict__ b1,
    const float* __restrict__ W2, const float* __restrict__ b2,
    const float* __restrict__ W3, const float* __restrict__ b3,
    const float* __restrict__ W4, const float* __restrict__ b4,
    float* __restrict__ out)
{
    __shared__ int   sIdx[4][512];
    __shared__ float sCnt[4][512];
    __shared__ float sF [4][132];
    __shared__ float sH1[4][64];
    __shared__ float sH2[4][32];
    __shared__ float sG [4][16];

    const int wid  = threadIdx.x >> 6;
    const int lane = threadIdx.x & 63;
    const int b    = blockIdx.x * 4 + wid;   // grid is exactly B/4

    const int q  = qents[b];
    const int qr = qrels[b];
    const int sl = ws[OFF_SLOT + q];
    const int* __restrict__   crow = ws + (size_t)sl * R_T;
    const float* __restrict__ REb  = RE + (size_t)b * (R_T * D_E);

    float reb = REb[qr * D_E + lane];

    // --- compact nonzero counts (ascending r, deterministic) ---
    int nnz = 0, degl = 0;
    for (int base = 0; base < R_T; base += 64) {
        int r = base + lane;
        int c = (r < R_T) ? crow[r] : 0;
        degl += c;
        unsigned long long m = __ballot(c != 0);
        if (c != 0) {
            int pos = nnz + (int)__popcll(m & ((1ull << lane) - 1ull));
            sIdx[wid][pos] = r;
            sCnt[wid][pos] = (float)c;
        }
        nnz += (int)__popcll(m);
    }
    // pad to multiple of 4 with zero-count entries (row 0 -> valid addr, 0 fma)
    if (lane < 4) {
        sIdx[wid][nnz + lane] = 0;
        sCnt[wid][nnz + lane] = 0.f;
    }
    #pragma unroll
    for (int off = 32; off; off >>= 1) degl += __shfl_xor(degl, off, 64);

    // --- sparse weighted sum: 4 rows/iter, branch-free ---
    const int g = lane >> 4;        // row group 0..3
    const int l = lane & 15;        // dwordx4 slot within row
    fv4 acc = {0.f, 0.f, 0.f, 0.f};
    #pragma unroll 4
    for (int k = 0; k < nnz; k += 4) {
        int   r = sIdx[wid][k + g];
        float c = sCnt[wid][k + g];
        fv4 v = *(const fv4*)(REb + r * D_E + 4 * l);
        acc[0] = fmaf(c, v[0], acc[0]);
        acc[1] = fmaf(c, v[1], acc[1]);
        acc[2] = fmaf(c, v[2], acc[2]);
        acc[3] = fmaf(c, v[3], acc[3]);
    }
    #pragma unroll
    for (int off = 16; off <= 32; off <<= 1) {
        acc[0] += __shfl_xor(acc[0], off, 64);
        acc[1] += __shfl_xor(acc[1], off, 64);
        acc[2] += __shfl_xor(acc[2], off, 64);
        acc[3] += __shfl_xor(acc[3], off, 64);
    }

    const float tot = (float)degl;
    const float inv = (degl > 0) ? (1.f / tot) : 0.f;

    sF[wid][lane] = reb;
    if (lane < 16) {
        float4* dst = (float4*)&sF[wid][64 + 4 * lane];
        *dst = make_float4(acc[0] * inv, acc[1] * inv, acc[2] * inv, acc[3] * inv);
    }
    if (lane == 0) {
        const float invE = (float)(1.0 / (double)E_E);
        float rf   = fminf((float)ws[OFF_RF + qr] * invE, 1.f);
        float dn   = fminf(tot * invE, 1.f);
        float dens = fminf((float)((double)E_E / ((double)N_N * (double)N_N)), 1.f);
        sF[wid][128] = rf;
        sF[wid][129] = dn;
        sF[wid][130] = rf;
        sF[wid][131] = dens;
    }
    // (no barrier: same-wave LDS write->read is in-order)

    // --- layer 1: 132 -> 64 ---
    float h = b1[lane];
    #pragma unroll 4
    for (int i = 0; i < 2 * D_E + 4; ++i)
        h = fmaf(sF[wid][i], W1[i * D_E + lane], h);
    sH1[wid][lane] = fmaxf(h, 0.f);

    // --- layer 2: 64 -> 32 ---
    if (lane < 32) {
        float s2 = b2[lane];
        #pragma unroll 4
        for (int i = 0; i < D_E; ++i)
            s2 = fmaf(sH1[wid][i], W2[i * 32 + lane], s2);
        sH2[wid][lane] = fmaxf(s2, 0.f);
    }

    // --- layer 3: 32 -> 16 ---
    if (lane < 16) {
        float s3 = b3[lane];
        #pragma unroll
        for (int i = 0; i < 32; ++i)
            s3 = fmaf(sH2[wid][i], W3[i * 16 + lane], s3);
        sG[wid][lane] = fmaxf(s3, 0.f);
    }

    // --- gate: 16 -> 1, sigmoid ---
    if (lane == 0) {
        float s4 = b4[0];
        #pragma unroll
        for (int i = 0; i < 16; ++i)
            s4 = fmaf(sG[wid][i], W4[i], s4);
        out[b] = 1.f / (1.f + expf(-s4));
    }
}

extern "C" void kernel_launch(void* const* d_in, const int* in_sizes, int n_in,
                              void* d_out, int out_size, void* d_ws, size_t ws_size,
                              hipStream_t stream) {
    const float* RE    = (const float*)d_in[0];
    const int*   qrels = (const int*)d_in[1];
    const int*   qents = (const int*)d_in[2];
    const int*   ei    = (const int*)d_in[3];
    const int*   et    = (const int*)d_in[4];
    const float* W1    = (const float*)d_in[5];
    const float* b1    = (const float*)d_in[6];
    const float* W2    = (const float*)d_in[7];
    const float* b2    = (const float*)d_in[8];
    const float* W3    = (const float*)d_in[9];
    const float* b3    = (const float*)d_in[10];
    const float* W4    = (const float*)d_in[11];
    const float* b4    = (const float*)d_in[12];
    float* out = (float*)d_out;
    int*   ws  = (int*)d_ws;

    k_init<<<2000, 256, 0, stream>>>(ws);
    k_build_slot<<<(B_Q + 255) / 256, 256, 0, stream>>>(qents, ws);
    k_edge_scatter<<<512, 256, 0, stream>>>(ei, et, ws);
    k_gate<<<B_Q / 4, 256, 0, stream>>>(RE, qrels, qents, ws,
                                        W1, b1, W2, b2, W3, b3, W4, b4, out);
}

// Round 14
// 77.091 us; speedup vs baseline: 1.6688x; 1.0954x over previous
//
#include <hip/hip_runtime.h>
#include <hip/hip_bf16.h>

#define B_Q 4096
#define R_T 500
#define D_E 64
#define N_N 100000
#define E_E 3200000
#define BM_W ((N_N + 31) / 32)   // 3125 words = 12.5 KB bitmap

typedef int   iv4 __attribute__((ext_vector_type(4)));
typedef float fv4 __attribute__((ext_vector_type(4)));

// ws layout (ints): Cm[B*R] | rel_freq[R] | slot[N] | bitmap[BM_W]
#define OFF_RF   ((size_t)B_Q * R_T)
#define OFF_SLOT (OFF_RF + R_T)
#define OFF_BM   (OFF_SLOT + N_N)

// ---------------------------------------------------------------------------
// init: zero Cm+rel_freq+bitmap, sentinel slot. uint4 stores, one dispatch.
// ---------------------------------------------------------------------------
__global__ __launch_bounds__(256) void k_init(int* __restrict__ ws) {
    const int t = blockIdx.x * blockDim.x + threadIdx.x;
    uint4* cm4 = (uint4*)ws;
    if (t < (B_Q * R_T) / 4) cm4[t] = make_uint4(0, 0, 0, 0);
    uint4* sl4 = (uint4*)(ws + OFF_SLOT);
    if (t < N_N / 4) sl4[t] = make_uint4(0x7f7f7f7fu, 0x7f7f7f7fu, 0x7f7f7f7fu, 0x7f7f7f7fu);
    if (t < R_T) ws[OFF_RF + t] = 0;
    if (t >= R_T && t < R_T + BM_W) ws[OFF_BM + (t - R_T)] = 0;
}

// ---------------------------------------------------------------------------
// slot[n] = min b with qents[b]==n; bitmap bit marks queried entities
// ---------------------------------------------------------------------------
__global__ __launch_bounds__(256) void k_build_slot(const int* __restrict__ qents,
                                                    int* __restrict__ ws) {
    int b = blockIdx.x * blockDim.x + threadIdx.x;
    if (b < B_Q) {
        int q = qents[b];
        atomicMin(&ws[OFF_SLOT + q], b);
        atomicOr(&ws[OFF_BM + (q >> 5)], 1 << (q & 31));
    }
}

// ---------------------------------------------------------------------------
// R13 shape (512 blocks, grid-stride, plain loads, LDS hist) + LDS BITMAP:
// the 12.5KB queried-entity bitmap is preloaded to LDS (6.4MB aggregate at
// 512 blocks) and probed there — removing 96% of divergent addresses from
// the TCP path (the measured ~35us wall). Survivors probe slot[] in L2.
// ---------------------------------------------------------------------------
__global__ __launch_bounds__(256) void k_edge_scatter(const int* __restrict__ ei,
                                                      const int* __restrict__ et,
                                                      int* __restrict__ ws) {
    __shared__ int      hist[R_T];
    __shared__ unsigned sbm[BM_W];
    const unsigned* __restrict__ gbm = (const unsigned*)(ws + OFF_BM);
    for (int i = threadIdx.x; i < R_T; i += blockDim.x) hist[i] = 0;
    for (int i = threadIdx.x; i < BM_W; i += blockDim.x) sbm[i] = gbm[i];
    __syncthreads();

    const int* __restrict__ slot = ws + OFF_SLOT;
    int* __restrict__       Cm   = ws;

    const int nthr = gridDim.x * blockDim.x;
    const int t    = blockIdx.x * blockDim.x + threadIdx.x;
    for (int g = t; g < E_E / 4; g += nthr) {
        const int e0 = g * 4;
        const iv4 s4 = *(const iv4*)(ei + e0);
        const iv4 d4 = *(const iv4*)(ei + E_E + e0);
        const iv4 t4 = *(const iv4*)(et + e0);
        #pragma unroll
        for (int j = 0; j < 4; ++j) {
            const int s  = s4[j];
            const int d  = d4[j];
            const int ty = t4[j];
            atomicAdd(&hist[ty], 1);
            if ((sbm[s >> 5] >> (s & 31)) & 1u) {
                atomicAdd(&Cm[(size_t)slot[s] * R_T + ty], 1);   // bit set => slot < B_Q
            }
            if (d != s && ((sbm[d >> 5] >> (d & 31)) & 1u)) {
                atomicAdd(&Cm[(size_t)slot[d] * R_T + ty], 1);
            }
        }
    }
    __syncthreads();
    for (int i = threadIdx.x; i < R_T; i += blockDim.x) {
        int v = hist[i];
        if (v) atomicAdd(&ws[OFF_RF + i], v);
    }
}

// ---------------------------------------------------------------------------
// One wave per query; 4 waves/block, ZERO block barriers. R13-proven body
// (plain cacheable loads).
// ---------------------------------------------------------------------------
__global__ __launch_bounds__(256) void k_gate(
    const float* __restrict__ RE,
    const int* __restrict__ qrels, const int* __restrict__ qents,
    const int* __restrict__ ws,
    const float* __restrict__ W1, const float* __restrict__ b1,
    const float* __restrict__ W2, const float* __restrict__ b2,
    const float* __restrict__ W3, const float* __restrict__ b3,
    const float* __restrict__ W4, const float* __restrict__ b4,
    float* __restrict__ out)
{
    __shared__ int   sIdx[4][512];
    __shared__ float sCnt[4][512];
    __shared__ float sF [4][132];
    __shared__ float sH1[4][64];
    __shared__ float sH2[4][32];
    __shared__ float sG [4][16];

    const int wid  = threadIdx.x >> 6;
    const int lane = threadIdx.x & 63;
    const int b    = blockIdx.x * 4 + wid;   // grid is exactly B/4

    const int q  = qents[b];
    const int qr = qrels[b];
    const int sl = ws[OFF_SLOT + q];
    const int* __restrict__   crow = ws + (size_t)sl * R_T;
    const float* __restrict__ REb  = RE + (size_t)b * (R_T * D_E);

    float reb = REb[qr * D_E + lane];

    // --- compact nonzero counts (ascending r, deterministic) ---
    int nnz = 0, degl = 0;
    for (int base = 0; base < R_T; base += 64) {
        int r = base + lane;
        int c = (r < R_T) ? crow[r] : 0;
        degl += c;
        unsigned long long m = __ballot(c != 0);
        if (c != 0) {
            int pos = nnz + (int)__popcll(m & ((1ull << lane) - 1ull));
            sIdx[wid][pos] = r;
            sCnt[wid][pos] = (float)c;
        }
        nnz += (int)__popcll(m);
    }
    // pad to multiple of 4 with zero-count entries (row 0 -> valid addr, 0 fma)
    if (lane < 4) {
        sIdx[wid][nnz + lane] = 0;
        sCnt[wid][nnz + lane] = 0.f;
    }
    #pragma unroll
    for (int off = 32; off; off >>= 1) degl += __shfl_xor(degl, off, 64);

    // --- sparse weighted sum: 4 rows/iter, branch-free ---
    const int g = lane >> 4;        // row group 0..3
    const int l = lane & 15;        // dwordx4 slot within row
    fv4 acc = {0.f, 0.f, 0.f, 0.f};
    #pragma unroll 4
    for (int k = 0; k < nnz; k += 4) {
        int   r = sIdx[wid][k + g];
        float c = sCnt[wid][k + g];
        fv4 v = *(const fv4*)(REb + r * D_E + 4 * l);
        acc[0] = fmaf(c, v[0], acc[0]);
        acc[1] = fmaf(c, v[1], acc[1]);
        acc[2] = fmaf(c, v[2], acc[2]);
        acc[3] = fmaf(c, v[3], acc[3]);
    }
    #pragma unroll
    for (int off = 16; off <= 32; off <<= 1) {
        acc[0] += __shfl_xor(acc[0], off, 64);
        acc[1] += __shfl_xor(acc[1], off, 64);
        acc[2] += __shfl_xor(acc[2], off, 64);
        acc[3] += __shfl_xor(acc[3], off, 64);
    }

    const float tot = (float)degl;
    const float inv = (degl > 0) ? (1.f / tot) : 0.f;

    sF[wid][lane] = reb;
    if (lane < 16) {
        float4* dst = (float4*)&sF[wid][64 + 4 * lane];
        *dst = make_float4(acc[0] * inv, acc[1] * inv, acc[2] * inv, acc[3] * inv);
    }
    if (lane == 0) {
        const float invE = (float)(1.0 / (double)E_E);
        float rf   = fminf((float)ws[OFF_RF + qr] * invE, 1.f);
        float dn   = fminf(tot * invE, 1.f);
        float dens = fminf((float)((double)E_E / ((double)N_N * (double)N_N)), 1.f);
        sF[wid][128] = rf;
        sF[wid][129] = dn;
        sF[wid][130] = rf;
        sF[wid][131] = dens;
    }
    // (no barrier: same-wave LDS write->read is in-order)

    // --- layer 1: 132 -> 64 ---
    float h = b1[lane];
    #pragma unroll 4
    for (int i = 0; i < 2 * D_E + 4; ++i)
        h = fmaf(sF[wid][i], W1[i * D_E + lane], h);
    sH1[wid][lane] = fmaxf(h, 0.f);

    // --- layer 2: 64 -> 32 ---
    if (lane < 32) {
        float s2 = b2[lane];
        #pragma unroll 4
        for (int i = 0; i < D_E; ++i)
            s2 = fmaf(sH1[wid][i], W2[i * 32 + lane], s2);
        sH2[wid][lane] = fmaxf(s2, 0.f);
    }

    // --- layer 3: 32 -> 16 ---
    if (lane < 16) {
        float s3 = b3[lane];
        #pragma unroll
        for (int i = 0; i < 32; ++i)
            s3 = fmaf(sH2[wid][i], W3[i * 16 + lane], s3);
        sG[wid][lane] = fmaxf(s3, 0.f);
    }

    // --- gate: 16 -> 1, sigmoid ---
    if (lane == 0) {
        float s4 = b4[0];
        #pragma unroll
        for (int i = 0; i < 16; ++i)
            s4 = fmaf(sG[wid][i], W4[i], s4);
        out[b] = 1.f / (1.f + expf(-s4));
    }
}

extern "C" void kernel_launch(void* const* d_in, const int* in_sizes, int n_in,
                              void* d_out, int out_size, void* d_ws, size_t ws_size,
                              hipStream_t stream) {
    const float* RE    = (const float*)d_in[0];
    const int*   qrels = (const int*)d_in[1];
    const int*   qents = (const int*)d_in[2];
    const int*   ei    = (const int*)d_in[3];
    const int*   et    = (const int*)d_in[4];
    const float* W1    = (const float*)d_in[5];
    const float* b1    = (const float*)d_in[6];
    const float* W2    = (const float*)d_in[7];
    const float* b2    = (const float*)d_in[8];
    const float* W3    = (const float*)d_in[9];
    const float* b3    = (const float*)d_in[10];
    const float* W4    = (const float*)d_in[11];
    const float* b4    = (const float*)d_in[12];
    float* out = (float*)d_out;
    int*   ws  = (int*)d_ws;

    k_init<<<2000, 256, 0, stream>>>(ws);
    k_build_slot<<<(B_Q + 255) / 256, 256, 0, stream>>>(qents, ws);
    k_edge_scatter<<<512, 256, 0, stream>>>(ei, et, ws);
    k_gate<<<B_Q / 4, 256, 0, stream>>>(RE, qrels, qents, ws,
                                        W1, b1, W2, b2, W3, b3, W4, b4, out);
}